// Round 6
// baseline (86.323 us; speedup 1.0000x reference)
//
#include <hip/hip_runtime.h>
#include <stdint.h>

typedef short v8s __attribute__((ext_vector_type(8)));
typedef float v4f __attribute__((ext_vector_type(4)));
typedef unsigned int u32;

#define CIN   320
#define COUT  320
#define HH    64
#define WW    64
#define BN    80         // couts per block -> 4 cob
#define CIB   32
#define NT    10         // ci tiles
#define XROWB 4224       // 66 cols * 64 B per xs row (big path)
#define WBUFE 23040      // ushort elements per weight buffer (46080 B)
#define NWI   45         // wave-wide gload_lds instrs per w tile

// ---- fallback-path (R3) constants ----
#define XS_C  40         // padded ci stride (80B rows) for x tile
#define XCOLS 66
#define XROWS 6
#define NWCH  (9*4*BN)

__device__ __forceinline__ float hf8_decode_f(int b) {
    int e = (b >> 3) & 15;
    int m = b & 7;
    float v = ldexpf((float)(e ? (8 + m) : m), e ? (e - 17) : -16);
    return ((b >> 7) & 1) ? -v : v;
}

__device__ __forceinline__ u32 cvt_pk_bf16(float lo, float hi) {
    u32 r;
    asm("v_cvt_pk_bf16_f32 %0, %1, %2" : "=v"(r) : "v"(lo), "v"(hi));
    return r;
}

// w_bits [Cout][Cin][3][3] -> w_deq [9][40 cig][320 co][8 ci] bf16 (LDS-final layout)
__global__ void dequant_kernel(const int* __restrict__ w_bits,
                               const int* __restrict__ b_bits,
                               unsigned short* __restrict__ w_deq,
                               float* __restrict__ b_deq) {
    int idx = blockIdx.x * 256 + threadIdx.x;   // 921600 = 3600 * 256
    int e    = idx & 7;
    int t    = idx >> 3;
    int co   = t % COUT;
    int t2   = t / COUT;
    int cig  = t2 % 40;
    int khkw = t2 / 40;
    int ci   = cig * 8 + e;
    float v = hf8_decode_f(w_bits[(co * CIN + ci) * 9 + khkw] & 0xFF);
    w_deq[idx] = (unsigned short)(__float_as_uint(v) >> 16);  // exact in bf16
    if (idx < COUT) b_deq[idx] = hf8_decode_f(b_bits[idx] & 0xFF);
}

// ============================ PATH A (big ws) ============================
// x f32 [n][ci][h][w] -> x_t bf16 [n][cig(10)][hp(66)][w(64)][ci32], halo rows zeroed.
__global__ __launch_bounds__(256) void convert_x_kernel(const float* __restrict__ x,
                                                        unsigned short* __restrict__ x_t) {
    __shared__ __align__(16) unsigned short lt[32 * 64];   // [ci][w] bf16
    const int b   = blockIdx.x;          // (n*10 + cig)*66 + hp
    const int hp  = b % 66;
    const int nc  = b / 66;              // n*10 + cig
    const int tid = threadIdx.x;
    char* outp = (char*)x_t + (size_t)b * 4096;
    if (hp == 0 || hp == 65) {
        *(int4*)(outp + tid * 16) = make_int4(0, 0, 0, 0);
        return;
    }
    const int h = hp - 1;
    // phase 1: read [32 ci][64 w] f32 coalesced, cvt, write LDS [ci][w] bf16
    {
        int ci = tid >> 3, wg = tid & 7;
        const float* src = x + ((size_t)nc * 32 + ci) * (HH * WW) + h * WW + wg * 8;
        float4 a = *(const float4*)src;
        float4 c = *(const float4*)(src + 4);
        u32 d0 = cvt_pk_bf16(a.x, a.y);
        u32 d1 = cvt_pk_bf16(a.z, a.w);
        u32 d2 = cvt_pk_bf16(c.x, c.y);
        u32 d3 = cvt_pk_bf16(c.z, c.w);
        *(int4*)&lt[ci * 64 + wg * 8] = make_int4(d0, d1, d2, d3);
    }
    __syncthreads();
    // phase 2 (FIXED): 128 threads = 32 w-pairs x 4 ci-octets; p in [0,16) -> ci < 32
    if (tid < 128) {
        int w2 = tid & 31, o = tid >> 5;     // w pair, ci octet (0..3)
        u32 A[4], B[4];
        #pragma unroll
        for (int j = 0; j < 4; ++j) {
            int p = o * 4 + j;               // ci pair 0..15
            u32 de = *(const u32*)&lt[(2 * p) * 64 + w2 * 2];
            u32 dq = *(const u32*)&lt[(2 * p + 1) * 64 + w2 * 2];
            A[j] = __builtin_amdgcn_perm(dq, de, 0x05040100u);  // w even: {de.lo, dq.lo}
            B[j] = __builtin_amdgcn_perm(dq, de, 0x07060302u);  // w odd:  {de.hi, dq.hi}
        }
        *(int4*)(outp + (2 * w2) * 64 + o * 16)     = make_int4(A[0], A[1], A[2], A[3]);
        *(int4*)(outp + (2 * w2 + 1) * 64 + o * 16) = make_int4(B[0], B[1], B[2], B[3]);
    }
}

__global__ __launch_bounds__(512, 2) void conv_big_kernel(
        const unsigned short* __restrict__ x_t,
        const unsigned short* __restrict__ w_deq,
        const float* __restrict__ b_deq,
        float* __restrict__ out) {
    __shared__ __align__(16) unsigned short xs[10 * 66 * 32];  // 42,240 B
    __shared__ __align__(16) unsigned short wl[2][WBUFE];      // 2 x 46,080 B

    const int tid  = threadIdx.x;
    const int bid  = blockIdx.x;
    const int cob  = bid >> 6;
    const int mb   = bid & 63;
    const int n    = mb >> 3;
    const int h0   = (mb & 7) << 3;
    const int wave = tid >> 6;
    const int lane = tid & 63;
    const int lhi  = lane >> 4;
    const int llo  = lane & 15;
    const int row_base = tid >> 8;
    const int col16    = tid & 255;

    if (tid < 320) {
        int row = tid >> 5, side = (tid >> 4) & 1, e = tid & 15;
        *(u32*)((char*)xs + row * XROWB + side * (65 * 64) + e * 4) = 0;
    }

    int woff[6];
    #pragma unroll
    for (int ii = 0; ii < 6; ++ii) {
        int i = wave + ii * 8;
        int c = i * 64 + lane;
        int co = c % BN;
        int q  = c / BN;
        int cig = q & 3, khkw = q >> 2;
        woff[ii] = ((khkw * 40 + cig) * COUT + cob * BN + co) << 4;
    }

    v4f acc[4][5];
    #pragma unroll
    for (int i = 0; i < 4; ++i)
        #pragma unroll
        for (int j = 0; j < 5; ++j)
            acc[i][j] = (v4f){0.f, 0.f, 0.f, 0.f};

    const char* xt_base = (const char*)x_t + ((size_t)(n * NT) * 66 + h0) * 4096;
    int4 xr[5];

    auto issueW = [&](int t) {
        unsigned short* wb = wl[t & 1];
        const char* ws = (const char*)w_deq + (size_t)t * 4 * COUT * 16;
        #pragma unroll
        for (int ii = 0; ii < 6; ++ii) {
            int i = wave + ii * 8;
            if (i < NWI) {
                __builtin_amdgcn_global_load_lds(
                    (const __attribute__((address_space(1))) u32*)(uintptr_t)(ws + woff[ii]),
                    (__attribute__((address_space(3))) u32*)(uintptr_t)((char*)wb + i * 1024),
                    16, 0, 0);
            }
        }
    };
    auto issueX = [&](int t) {
        const char* xb = xt_base + (size_t)t * (66 * 4096);
        #pragma unroll
        for (int j = 0; j < 5; ++j)
            xr[j] = *(const int4*)(xb + (row_base + 2 * j) * 4096 + col16 * 16);
    };
    auto writeX = [&]() {
        #pragma unroll
        for (int j = 0; j < 5; ++j)
            *(int4*)((char*)xs + (row_base + 2 * j) * XROWB + 64 + col16 * 16) = xr[j];
    };
    auto compute = [&](int sel) {
        const unsigned short* wb = wl[sel];
        #pragma unroll
        for (int khkw = 0; khkw < 9; ++khkw) {
            const int kh = khkw / 3, kw = khkw % 3;
            v8s bfr[5];
            #pragma unroll
            for (int nr = 0; nr < 5; ++nr)
                bfr[nr] = *(const v8s*)&wb[((khkw * 4 + lhi) * BN + nr * 16 + llo) * 8];
            #pragma unroll
            for (int mr = 0; mr < 4; ++mr) {
                v8s afr = *(const v8s*)&xs[((wave + kh) * 66 + mr * 16 + llo + kw) * 32 + lhi * 8];
                #pragma unroll
                for (int nr = 0; nr < 5; ++nr)
                    acc[mr][nr] = __builtin_amdgcn_mfma_f32_16x16x32_bf16(
                        afr, bfr[nr], acc[mr][nr], 0, 0, 0);
            }
        }
    };

    issueW(0);
    issueX(0);
    __syncthreads();          // vmcnt(0): w0 in LDS, x0 in regs; halo zeros done
    writeX();
    __syncthreads();          // xs ready

    for (int t = 0; t < NT; ++t) {
        if (t + 1 < NT) { issueW(t + 1); issueX(t + 1); }
        compute(t & 1);
        __syncthreads();      // xs reads done; vmcnt(0): w(t+1) landed, x(t+1) in regs
        if (t + 1 < NT) writeX();
        __syncthreads();
    }

    const int h = h0 + wave;
    #pragma unroll
    for (int nr = 0; nr < 5; ++nr) {
        int co = cob * BN + nr * 16 + llo;
        float bias = b_deq[co];
        float* op = out + ((size_t)(n * COUT + co) * HH + h) * WW;
        #pragma unroll
        for (int mr = 0; mr < 4; ++mr) {
            int wc = mr * 16 + lhi * 4;
            float4 o;
            o.x = acc[mr][nr][0] + bias;
            o.y = acc[mr][nr][1] + bias;
            o.z = acc[mr][nr][2] + bias;
            o.w = acc[mr][nr][3] + bias;
            *(float4*)(op + wc) = o;
        }
    }
}

// ============================ PATH B (R3, proven) ============================
__global__ __launch_bounds__(256, 2) void conv_mfma_kernel(
        const float* __restrict__ x,
        const unsigned short* __restrict__ w_deq,
        const float* __restrict__ b_deq,
        float* __restrict__ out) {
    __shared__ __align__(16) unsigned short xs[XROWS * XCOLS * XS_C];
    __shared__ __align__(16) unsigned short wl[NWCH * 8];

    const int tid  = threadIdx.x;
    const int bid  = blockIdx.x;
    const int cob  = bid >> 7;
    const int mb   = bid & 127;
    const int n    = mb >> 4;
    const int h0   = (mb & 15) << 2;
    const int wave = tid >> 6;
    const int lane = tid & 63;
    const int lhi  = lane >> 4;
    const int llo  = lane & 15;
    const int ciL2 = tid & 15;
    const int seg  = tid >> 4;

    for (int i = tid; i < XROWS * 2 * XS_C; i += 256) {
        int r  = i / (2 * XS_C);
        int tt = i - r * (2 * XS_C);
        int c  = (tt >= XS_C) ? 65 : 0;
        int ci = (tt >= XS_C) ? (tt - XS_C) : tt;
        xs[(r * XCOLS + c) * XS_C + ci] = 0;
    }

    v4f acc[4][5];
    #pragma unroll
    for (int i = 0; i < 4; ++i)
        #pragma unroll
        for (int j = 0; j < 5; ++j)
            acc[i][j] = (v4f){0.f, 0.f, 0.f, 0.f};

    int woff[12];
    #pragma unroll
    for (int ii = 0; ii < 12; ++ii) {
        int i = wave + ii * 4;
        if (i < NWCH / 64) {
            int c    = i * 64 + lane;
            int co   = c % BN;
            int q    = c / BN;
            int cig  = q & 3;
            int khkw = q >> 2;
            woff[ii] = ((khkw * 40 + cig) * COUT + cob * BN + co) * 16;
        } else {
            woff[ii] = 0;
        }
    }

    const float* xbase = x + ((size_t)(n * CIN) + 2 * ciL2) * (HH * WW);

    for (int t = 0; t < 10; ++t) {
        const int ci0 = t * CIB;
        __syncthreads();

        float4 xa[XROWS], xb[XROWS];
        {
            const float* xp0 = xbase + (size_t)ci0 * (HH * WW);
            const float* xp1 = xp0 + HH * WW;
            #pragma unroll
            for (int r = 0; r < XROWS; ++r) {
                int gh = h0 - 1 + r;
                if (gh >= 0 && gh < HH) {
                    xa[r] = *(const float4*)(xp0 + gh * WW + seg * 4);
                    xb[r] = *(const float4*)(xp1 + gh * WW + seg * 4);
                } else {
                    xa[r] = make_float4(0.f, 0.f, 0.f, 0.f);
                    xb[r] = make_float4(0.f, 0.f, 0.f, 0.f);
                }
            }
        }
        {
            const char* wb = (const char*)w_deq + (size_t)(ci0 >> 3) * (COUT * 16);
            #pragma unroll
            for (int ii = 0; ii < 12; ++ii) {
                int i = wave + ii * 4;
                if (i < NWCH / 64) {
                    __builtin_amdgcn_global_load_lds(
                        (const __attribute__((address_space(1))) u32*)(uintptr_t)(wb + woff[ii]),
                        (__attribute__((address_space(3))) u32*)(uintptr_t)((char*)wl + i * 1024),
                        16, 0, 0);
                }
            }
        }
        #pragma unroll
        for (int r = 0; r < XROWS; ++r) {
            u32 p0 = cvt_pk_bf16(xa[r].x, xb[r].x);
            u32 p1 = cvt_pk_bf16(xa[r].y, xb[r].y);
            u32 p2 = cvt_pk_bf16(xa[r].z, xb[r].z);
            u32 p3 = cvt_pk_bf16(xa[r].w, xb[r].w);
            int cbase = r * XCOLS + 1 + seg * 4;
            *(u32*)&xs[(cbase + 0) * XS_C + 2 * ciL2] = p0;
            *(u32*)&xs[(cbase + 1) * XS_C + 2 * ciL2] = p1;
            *(u32*)&xs[(cbase + 2) * XS_C + 2 * ciL2] = p2;
            *(u32*)&xs[(cbase + 3) * XS_C + 2 * ciL2] = p3;
        }

        __syncthreads();

        #pragma unroll
        for (int khkw = 0; khkw < 9; ++khkw) {
            const int kh = khkw / 3, kw = khkw % 3;
            v8s bfr[5];
            #pragma unroll
            for (int nr = 0; nr < 5; ++nr)
                bfr[nr] = *(const v8s*)&wl[((khkw * 4 + lhi) * BN + nr * 16 + llo) * 8];
            #pragma unroll
            for (int mr = 0; mr < 4; ++mr) {
                v8s afr = *(const v8s*)&xs[((wave + kh) * XCOLS + mr * 16 + llo + kw) * XS_C + lhi * 8];
                #pragma unroll
                for (int nr = 0; nr < 5; ++nr)
                    acc[mr][nr] = __builtin_amdgcn_mfma_f32_16x16x32_bf16(
                        afr, bfr[nr], acc[mr][nr], 0, 0, 0);
            }
        }
    }

    const int h = h0 + wave;
    #pragma unroll
    for (int nr = 0; nr < 5; ++nr) {
        int co = cob * BN + nr * 16 + llo;
        float bias = b_deq[co];
        float* op = out + ((size_t)((n * COUT + co) * HH + h)) * WW;
        #pragma unroll
        for (int mr = 0; mr < 4; ++mr) {
            int wc = mr * 16 + lhi * 4;
            float4 o;
            o.x = acc[mr][nr][0] + bias;
            o.y = acc[mr][nr][1] + bias;
            o.z = acc[mr][nr][2] + bias;
            o.w = acc[mr][nr][3] + bias;
            *(float4*)(op + wc) = o;
        }
    }
}

extern "C" void kernel_launch(void* const* d_in, const int* in_sizes, int n_in,
                              void* d_out, int out_size, void* d_ws, size_t ws_size,
                              hipStream_t stream) {
    const float* x      = (const float*)d_in[0];
    const int*   w_bits = (const int*)d_in[1];
    const int*   b_bits = (const int*)d_in[2];
    float*       out    = (float*)d_out;

    unsigned short* w_deq = (unsigned short*)d_ws;                       // 1,843,200 B
    float*          b_deq = (float*)((char*)d_ws + (size_t)9 * 40 * COUT * 8 * 2);
    unsigned short* x_t   = (unsigned short*)((char*)d_ws + (2u << 20)); // big path only

    dequant_kernel<<<3600, 256, 0, stream>>>(w_bits, b_bits, w_deq, b_deq);

    if (ws_size >= (24ull << 20)) {
        convert_x_kernel<<<8 * NT * 66, 256, 0, stream>>>(x, x_t);
        conv_big_kernel<<<256, 512, 0, stream>>>(x_t, w_deq, b_deq, out);
    } else {
        conv_mfma_kernel<<<512, 256, 0, stream>>>(x, w_deq, b_deq, out);
    }
}

// Round 7
// 67.278 us; speedup vs baseline: 1.2831x; 1.2831x over previous
//
#include <hip/hip_runtime.h>
#include <stdint.h>

typedef short v8s __attribute__((ext_vector_type(8)));
typedef float v4f __attribute__((ext_vector_type(4)));
typedef unsigned int u32;

#define CIN   320
#define COUT  320
#define HH    64
#define WW    64
#define BN    80
#define NT    10
// conv LDS geometry
#define XSB   25344      // 6 rows * 66 cols * 64B, one x buffer
#define WLB   15360      // 3 kw * 4 cig * 80 co * 16B, one weight kh-slice
#define WKHB  61440      // bytes per (t,kh) slice in w_deq2: 3*4*320*16

// ---- fallback-path (R3) constants ----
#define XS_C  40
#define XCOLS 66
#define XROWS 6
#define NWCH  (9*4*BN)

__device__ __forceinline__ float hf8_decode_f(int b) {
    int e = (b >> 3) & 15;
    int m = b & 7;
    float v = ldexpf((float)(e ? (8 + m) : m), e ? (e - 17) : -16);
    return ((b >> 7) & 1) ? -v : v;
}

__device__ __forceinline__ u32 cvt_pk_bf16(float lo, float hi) {
    u32 r;
    asm("v_cvt_pk_bf16_f32 %0, %1, %2" : "=v"(r) : "v"(lo), "v"(hi));
    return r;
}

__device__ __forceinline__ void gload16(const void* g, void* l) {
    __builtin_amdgcn_global_load_lds(
        (const __attribute__((address_space(1))) u32*)(uintptr_t)g,
        (__attribute__((address_space(3))) u32*)(uintptr_t)l, 16, 0, 0);
}

// ============ merged pre-pass: dequant (blocks 0..3599) + convert (3600..8879) ============
// w_deq2 layout: [t(10)][kh(3)][kw(3)][cig(4)][co(320)][e(8)] bf16
// x_t   layout: [n(8)][cig(10)][hp(66)][w(64)][ci(32)] bf16, hp halo rows zeroed
__global__ __launch_bounds__(256) void prepass_kernel(const int* __restrict__ w_bits,
                                                      const int* __restrict__ b_bits,
                                                      const float* __restrict__ x,
                                                      unsigned short* __restrict__ w_deq2,
                                                      float* __restrict__ b_deq,
                                                      unsigned short* __restrict__ x_t) {
    __shared__ __align__(16) unsigned short lt[32 * 64];
    const int tid = threadIdx.x;
    if (blockIdx.x < 3600) {
        // ---- dequant role ----
        int o  = blockIdx.x * 256 + tid;          // 921600 ushorts
        int e  = o & 7;
        int c2 = o >> 3;
        int co = c2 % COUT;
        int c3 = c2 / COUT;
        int cig = c3 & 3;
        int c4 = c3 >> 2;
        int kw = c4 % 3;
        int c5 = c4 / 3;
        int kh = c5 % 3;
        int t  = c5 / 3;
        int ci = t * 32 + cig * 8 + e;
        float v = hf8_decode_f(w_bits[(co * CIN + ci) * 9 + kh * 3 + kw] & 0xFF);
        w_deq2[o] = (unsigned short)(__float_as_uint(v) >> 16);
        if (o < COUT) b_deq[o] = hf8_decode_f(b_bits[o] & 0xFF);
        return;
    }
    // ---- convert role (R6-proven) ----
    const int b  = blockIdx.x - 3600;    // (n*10 + cig)*66 + hp
    const int hp = b % 66;
    const int nc = b / 66;
    char* outp = (char*)x_t + (size_t)b * 4096;
    if (hp == 0 || hp == 65) {
        *(int4*)(outp + tid * 16) = make_int4(0, 0, 0, 0);
        return;
    }
    const int h = hp - 1;
    {
        int ci = tid >> 3, wg = tid & 7;
        const float* src = x + ((size_t)nc * 32 + ci) * (HH * WW) + h * WW + wg * 8;
        float4 a = *(const float4*)src;
        float4 c = *(const float4*)(src + 4);
        u32 d0 = cvt_pk_bf16(a.x, a.y);
        u32 d1 = cvt_pk_bf16(a.z, a.w);
        u32 d2 = cvt_pk_bf16(c.x, c.y);
        u32 d3 = cvt_pk_bf16(c.z, c.w);
        *(int4*)&lt[ci * 64 + wg * 8] = make_int4(d0, d1, d2, d3);
    }
    __syncthreads();
    if (tid < 128) {
        int w2 = tid & 31, o = tid >> 5;
        u32 A[4], B[4];
        #pragma unroll
        for (int j = 0; j < 4; ++j) {
            int p = o * 4 + j;
            u32 de = *(const u32*)&lt[(2 * p) * 64 + w2 * 2];
            u32 dq = *(const u32*)&lt[(2 * p + 1) * 64 + w2 * 2];
            A[j] = __builtin_amdgcn_perm(dq, de, 0x05040100u);
            B[j] = __builtin_amdgcn_perm(dq, de, 0x07060302u);
        }
        *(int4*)(outp + (2 * w2) * 64 + o * 16)     = make_int4(A[0], A[1], A[2], A[3]);
        *(int4*)(outp + (2 * w2 + 1) * 64 + o * 16) = make_int4(B[0], B[1], B[2], B[3]);
    }
}

// ============ conv: 256 thr, 4 waves, 2 blocks/CU, kh-phase pipeline ============
__global__ __launch_bounds__(256, 2) void conv_phase_kernel(
        const unsigned short* __restrict__ x_t,
        const unsigned short* __restrict__ w_deq2,
        const float* __restrict__ b_deq,
        float* __restrict__ out) {
    __shared__ __align__(16) unsigned short xs[2 * XSB / 2];   // 50,688 B
    __shared__ __align__(16) unsigned short wl[2 * WLB / 2];   // 30,720 B  (total 81,408)

    const int tid  = threadIdx.x;
    const int bid  = blockIdx.x;
    const int cob  = bid >> 7;        // 4 cout blocks; same-mb blocks (d=128) share an XCD
    const int mb   = bid & 127;       // 8 img x 16 rowgroups
    const int n    = mb >> 4;
    const int h0   = (mb & 15) << 2;  // 4 output rows per block
    const int wave = tid >> 6;        // wave owns output row h0+wave
    const int lane = tid & 63;
    const int lhi  = lane >> 4;
    const int llo  = lane & 15;

    // zero halo cols (xs col 0 and 65) of both buffers, once
    for (int i = tid; i < 384; i += 256) {
        int buf = i / 192;
        int r   = (i - buf * 192) >> 5;
        int rem = i & 31;
        int side = rem >> 4, e = rem & 15;
        *(u32*)((char*)xs + buf * XSB + r * 4224 + side * 4160 + e * 4) = 0;
    }

    // per-lane constant global offsets for weight gloads (chunk c = i*64+lane, i = wave*4+ii)
    int woffW[4];
    #pragma unroll
    for (int ii = 0; ii < 4; ++ii) {
        int i = wave * 4 + ii;
        int c = i * 64 + lane;                 // < 960 for i < 15
        int q = c / BN;                        // kw*4+cig
        int co = c - q * BN;
        woffW[ii] = (q * COUT + cob * BN + co) << 4;
    }

    v4f acc[4][5];
    #pragma unroll
    for (int i = 0; i < 4; ++i)
        #pragma unroll
        for (int j = 0; j < 5; ++j)
            acc[i][j] = (v4f){0.f, 0.f, 0.f, 0.f};

    const char* xt_lane = (const char*)x_t + ((size_t)(n * NT) * 66 + h0) * 4096 + lane * 16;

    auto issueW = [&](int t_, int kh_, int wb) {
        const char* base = (const char*)w_deq2 + (size_t)(t_ * 3 + kh_) * WKHB;
        char* dst = (char*)wl + wb * WLB + wave * 4096;
        #pragma unroll
        for (int ii = 0; ii < 4; ++ii) {
            if (wave * 4 + ii < 15)
                gload16(base + woffW[ii], dst + ii * 1024);
        }
    };
    auto issueX = [&](int t_, int xb) {
        const char* src = xt_lane + (size_t)t_ * (66 * 4096);
        char* dstb = (char*)xs + xb * XSB + 64;
        #pragma unroll
        for (int m = 0; m < 6; ++m) {
            int id = wave * 6 + m;            // 0..23
            int j = id >> 2, k = id & 3;
            gload16(src + j * 4096 + k * 1024, dstb + j * 4224 + k * 1024);
        }
    };
    auto computeKh = [&](int kh, int xb, int wb) {
        const char* xp = (const char*)xs + xb * XSB + (wave + kh) * 4224;
        const unsigned short* wp = wl + wb * (WLB / 2);
        __builtin_amdgcn_s_setprio(1);
        #pragma unroll
        for (int kw = 0; kw < 3; ++kw) {
            v8s bfr[5];
            #pragma unroll
            for (int nr = 0; nr < 5; ++nr)
                bfr[nr] = *(const v8s*)&wp[((kw * 4 + lhi) * BN + nr * 16 + llo) * 8];
            #pragma unroll
            for (int mr = 0; mr < 4; ++mr) {
                v8s afr = *(const v8s*)(xp + (mr * 16 + llo + kw) * 64 + lhi * 16);
                #pragma unroll
                for (int nr = 0; nr < 5; ++nr)
                    acc[mr][nr] = __builtin_amdgcn_mfma_f32_16x16x32_bf16(
                        afr, bfr[nr], acc[mr][nr], 0, 0, 0);
            }
        }
        __builtin_amdgcn_s_setprio(0);
    };

    // prologue: stage tile 0 (w slice kh=0 -> wl[0], x tile 0 -> xs[0])
    issueW(0, 0, 0);
    issueX(0, 0);

    for (int t = 0; t < NT; ++t) {
        const int p = t & 1;
        // phase kh=0: uses wl[p], xs[p]
        __syncthreads();                       // drains: loads for this phase landed
        issueW(t, 1, p ^ 1);
        computeKh(0, p, p);
        // phase kh=1: uses wl[p^1]
        __syncthreads();
        issueW(t, 2, p);
        computeKh(1, p, p ^ 1);
        // phase kh=2: uses wl[p]
        __syncthreads();
        if (t + 1 < NT) { issueW(t + 1, 0, p ^ 1); issueX(t + 1, p ^ 1); }
        computeKh(2, p, p);
    }

    // epilogue: bias + float4 stores
    const int h = h0 + wave;
    #pragma unroll
    for (int nr = 0; nr < 5; ++nr) {
        int co = cob * BN + nr * 16 + llo;      // D col = lane&15
        float bias = b_deq[co];
        float* op = out + ((size_t)(n * COUT + co) * HH + h) * WW;
        #pragma unroll
        for (int mr = 0; mr < 4; ++mr) {
            int wc = mr * 16 + lhi * 4;         // D row = (lane>>4)*4 + reg
            float4 o;
            o.x = acc[mr][nr][0] + bias;
            o.y = acc[mr][nr][1] + bias;
            o.z = acc[mr][nr][2] + bias;
            o.w = acc[mr][nr][3] + bias;
            *(float4*)(op + wc) = o;
        }
    }
}

// ============================ PATH B (R3, proven fallback) ============================
__global__ void dequantB_kernel(const int* __restrict__ w_bits,
                                const int* __restrict__ b_bits,
                                unsigned short* __restrict__ w_deq,
                                float* __restrict__ b_deq) {
    int idx = blockIdx.x * 256 + threadIdx.x;
    int e    = idx & 7;
    int t    = idx >> 3;
    int co   = t % COUT;
    int t2   = t / COUT;
    int cig  = t2 % 40;
    int khkw = t2 / 40;
    int ci   = cig * 8 + e;
    float v = hf8_decode_f(w_bits[(co * CIN + ci) * 9 + khkw] & 0xFF);
    w_deq[idx] = (unsigned short)(__float_as_uint(v) >> 16);
    if (idx < COUT) b_deq[idx] = hf8_decode_f(b_bits[idx] & 0xFF);
}

__global__ __launch_bounds__(256, 2) void conv_mfma_kernel(
        const float* __restrict__ x,
        const unsigned short* __restrict__ w_deq,
        const float* __restrict__ b_deq,
        float* __restrict__ out) {
    __shared__ __align__(16) unsigned short xs[XROWS * XCOLS * XS_C];
    __shared__ __align__(16) unsigned short wl[NWCH * 8];

    const int tid  = threadIdx.x;
    const int bid  = blockIdx.x;
    const int cob  = bid >> 7;
    const int mb   = bid & 127;
    const int n    = mb >> 4;
    const int h0   = (mb & 15) << 2;
    const int wave = tid >> 6;
    const int lane = tid & 63;
    const int lhi  = lane >> 4;
    const int llo  = lane & 15;
    const int ciL2 = tid & 15;
    const int seg  = tid >> 4;

    for (int i = tid; i < XROWS * 2 * XS_C; i += 256) {
        int r  = i / (2 * XS_C);
        int tt = i - r * (2 * XS_C);
        int c  = (tt >= XS_C) ? 65 : 0;
        int ci = (tt >= XS_C) ? (tt - XS_C) : tt;
        xs[(r * XCOLS + c) * XS_C + ci] = 0;
    }

    v4f acc[4][5];
    #pragma unroll
    for (int i = 0; i < 4; ++i)
        #pragma unroll
        for (int j = 0; j < 5; ++j)
            acc[i][j] = (v4f){0.f, 0.f, 0.f, 0.f};

    int woff[12];
    #pragma unroll
    for (int ii = 0; ii < 12; ++ii) {
        int i = wave + ii * 4;
        if (i < NWCH / 64) {
            int c    = i * 64 + lane;
            int co   = c % BN;
            int q    = c / BN;
            int cig  = q & 3;
            int khkw = q >> 2;
            woff[ii] = ((khkw * 40 + cig) * COUT + cob * BN + co) * 16;
        } else {
            woff[ii] = 0;
        }
    }

    const float* xbase = x + ((size_t)(n * CIN) + 2 * ciL2) * (HH * WW);

    for (int t = 0; t < 10; ++t) {
        const int ci0 = t * 32;
        __syncthreads();

        float4 xa[XROWS], xb[XROWS];
        {
            const float* xp0 = xbase + (size_t)ci0 * (HH * WW);
            const float* xp1 = xp0 + HH * WW;
            #pragma unroll
            for (int r = 0; r < XROWS; ++r) {
                int gh = h0 - 1 + r;
                if (gh >= 0 && gh < HH) {
                    xa[r] = *(const float4*)(xp0 + gh * WW + seg * 4);
                    xb[r] = *(const float4*)(xp1 + gh * WW + seg * 4);
                } else {
                    xa[r] = make_float4(0.f, 0.f, 0.f, 0.f);
                    xb[r] = make_float4(0.f, 0.f, 0.f, 0.f);
                }
            }
        }
        {
            const char* wb = (const char*)w_deq + (size_t)(ci0 >> 3) * (COUT * 16);
            #pragma unroll
            for (int ii = 0; ii < 12; ++ii) {
                int i = wave + ii * 4;
                if (i < NWCH / 64)
                    gload16(wb + woff[ii], (char*)wl + i * 1024);
            }
        }
        #pragma unroll
        for (int r = 0; r < XROWS; ++r) {
            u32 p0 = cvt_pk_bf16(xa[r].x, xb[r].x);
            u32 p1 = cvt_pk_bf16(xa[r].y, xb[r].y);
            u32 p2 = cvt_pk_bf16(xa[r].z, xb[r].z);
            u32 p3 = cvt_pk_bf16(xa[r].w, xb[r].w);
            int cbase = r * XCOLS + 1 + seg * 4;
            *(u32*)&xs[(cbase + 0) * XS_C + 2 * ciL2] = p0;
            *(u32*)&xs[(cbase + 1) * XS_C + 2 * ciL2] = p1;
            *(u32*)&xs[(cbase + 2) * XS_C + 2 * ciL2] = p2;
            *(u32*)&xs[(cbase + 3) * XS_C + 2 * ciL2] = p3;
        }

        __syncthreads();

        #pragma unroll
        for (int khkw = 0; khkw < 9; ++khkw) {
            const int kh = khkw / 3, kw = khkw % 3;
            v8s bfr[5];
            #pragma unroll
            for (int nr = 0; nr < 5; ++nr)
                bfr[nr] = *(const v8s*)&wl[((khkw * 4 + lhi) * BN + nr * 16 + llo) * 8];
            #pragma unroll
            for (int mr = 0; mr < 4; ++mr) {
                v8s afr = *(const v8s*)&xs[((wave + kh) * XCOLS + mr * 16 + llo + kw) * XS_C + lhi * 8];
                #pragma unroll
                for (int nr = 0; nr < 5; ++nr)
                    acc[mr][nr] = __builtin_amdgcn_mfma_f32_16x16x32_bf16(
                        afr, bfr[nr], acc[mr][nr], 0, 0, 0);
            }
        }
    }

    const int h = h0 + wave;
    #pragma unroll
    for (int nr = 0; nr < 5; ++nr) {
        int co = cob * BN + nr * 16 + llo;
        float bias = b_deq[co];
        float* op = out + ((size_t)((n * COUT + co) * HH + h)) * WW;
        #pragma unroll
        for (int mr = 0; mr < 4; ++mr) {
            int wc = mr * 16 + lhi * 4;
            float4 o;
            o.x = acc[mr][nr][0] + bias;
            o.y = acc[mr][nr][1] + bias;
            o.z = acc[mr][nr][2] + bias;
            o.w = acc[mr][nr][3] + bias;
            *(float4*)(op + wc) = o;
        }
    }
}

extern "C" void kernel_launch(void* const* d_in, const int* in_sizes, int n_in,
                              void* d_out, int out_size, void* d_ws, size_t ws_size,
                              hipStream_t stream) {
    const float* x      = (const float*)d_in[0];
    const int*   w_bits = (const int*)d_in[1];
    const int*   b_bits = (const int*)d_in[2];
    float*       out    = (float*)d_out;

    unsigned short* w_deq = (unsigned short*)d_ws;                       // 1,843,200 B
    float*          b_deq = (float*)((char*)d_ws + 1843200);
    unsigned short* x_t   = (unsigned short*)((char*)d_ws + (2u << 20)); // 21.6 MB

    if (ws_size >= (24ull << 20)) {
        prepass_kernel<<<8880, 256, 0, stream>>>(w_bits, b_bits, x, w_deq, b_deq, x_t);
        conv_phase_kernel<<<512, 256, 0, stream>>>(x_t, w_deq, b_deq, out);
    } else {
        dequantB_kernel<<<3600, 256, 0, stream>>>(w_bits, b_bits, w_deq, b_deq);
        conv_mfma_kernel<<<512, 256, 0, stream>>>(x, w_deq, b_deq, out);
    }
}